// Round 8
// baseline (164.813 us; speedup 1.0000x reference)
//
#include <hip/hip_runtime.h>

// LSTM (B=8192, T=168, F=64, H=50) + MLP head, fused, f16 MFMA + fp32 state.
// Round 8: two interleaved row-groups (A/B) per block, alternating barrier
// windows (336 windows/block). All LDS producer->consumer distances are 2
// windows, so h/ax writes are DEFERRED to the next window's start (flush),
// pulling write latency + gate tails off the per-window critical path.
// 256 blocks x 512 thr (waves 0-3 x-role, 4-7 h-role), 1 block/CU.

#define B_N 8192
#define T_N 168
#define F_N 64
#define H_N 50
#define HEAD_N 100
#define ROWSTRIDE (T_N * F_N)  // 10752

typedef _Float16 f16x8 __attribute__((ext_vector_type(8)));
typedef _Float16 f16x4 __attribute__((ext_vector_type(4)));
typedef float    f32x4 __attribute__((ext_vector_type(4)));

#define LOG2E  1.4426950408889634f
#define LOG2E2 2.8853900817779268f

#define MFMA __builtin_amdgcn_mfma_f32_16x16x32_f16

// LDS-only barrier: drain own LDS ops, barrier, compiler fence both sides.
#define BAR()                                                        \
    do {                                                             \
        asm volatile("s_waitcnt lgkmcnt(0)" ::: "memory");           \
        __builtin_amdgcn_s_barrier();                                \
        asm volatile("" ::: "memory");                               \
    } while (0)

__device__ __forceinline__ float rcp_f(float v) { return __builtin_amdgcn_rcpf(v); }
#if __has_builtin(__builtin_amdgcn_exp2f)
__device__ __forceinline__ float exp2_f(float v) { return __builtin_amdgcn_exp2f(v); }
#else
__device__ __forceinline__ float exp2_f(float v) { return __expf(0.6931471805599453f * v); }
#endif

__launch_bounds__(512, 2)
__global__ void lstm_fused(const float* __restrict__ x,
                           const float* __restrict__ Wx,
                           const float* __restrict__ Wh,
                           const float* __restrict__ b,
                           const float* __restrict__ W1,
                           const float* __restrict__ b1,
                           const float* __restrict__ W2,
                           const float* __restrict__ b2,
                           float* __restrict__ out)
{
    // [group][buf] double-buffered tiles; stride 72 f16 rows (2-way alias only)
    __shared__ alignas(16) _Float16 xb[2][2][16][72];
    __shared__ alignas(16) _Float16 hb[2][2][16][72];
    __shared__ alignas(16) float    axb[2][2][4][4][64][4];  // [G][buf][ut][gate][lane][4]

    const int tid  = threadIdx.x;
    const int lane = tid & 63;
    const int w    = tid >> 6;         // 0..7; 0-3 x-waves, 4-7 h-waves
    const int ut   = w & 3;            // unit-tile (16 units each)
    const int rowA = lane & 15;
    const int kg   = lane >> 4;
    const int R0   = blockIdx.x * 32;  // 32 batch rows (groups A: +0..15, B: +16..31)
    const int jl   = ut * 16 + rowA;
    const bool jv  = (jl < H_N);

    // zero h(0) for both groups (buf 0)
    for (int idx = tid; idx < 16 * 72; idx += 512) {
        ((_Float16*)hb[0][0])[idx] = (_Float16)0.0f;
        ((_Float16*)hb[1][0])[idx] = (_Float16)0.0f;
    }

    if (w < 4) {
        // ---------------- x-role ------------------------------------------
        f16x8 wxf[4][2];
        float bg[4];
        #pragma unroll
        for (int g = 0; g < 4; ++g) {
            const float sc = (g == 2) ? LOG2E2 : LOG2E;
            bg[g] = jv ? b[g * H_N + jl] * sc : 0.0f;
            #pragma unroll
            for (int ks = 0; ks < 2; ++ks) {
                f16x8 v;
                #pragma unroll
                for (int i = 0; i < 8; ++i) {
                    int k = ks * 32 + kg * 8 + i;
                    v[i] = (_Float16)(jv ? Wx[k * 200 + g * H_N + jl] * sc : 0.0f);
                }
                wxf[g][ks] = v;
            }
        }

        const int xr  = (tid >> 4) & 15;
        const int xf0 = (tid & 15) * 4;
        const float* xrowA = x + (size_t)(R0 + xr) * ROWSTRIDE + xf0;
        const float* xrowB = x + (size_t)(R0 + 16 + xr) * ROWSTRIDE + xf0;
        f32x4 xprA0, xprA1, xprB0, xprB1;
        {
            f32x4 a0 = *reinterpret_cast<const f32x4*>(xrowA);
            f32x4 a1 = *reinterpret_cast<const f32x4*>(xrowA + F_N);
            xprA0 = *reinterpret_cast<const f32x4*>(xrowA + 2 * F_N);
            xprA1 = *reinterpret_cast<const f32x4*>(xrowA + 3 * F_N);
            f32x4 b0 = *reinterpret_cast<const f32x4*>(xrowB);
            f32x4 b1v = *reinterpret_cast<const f32x4*>(xrowB + F_N);
            xprB0 = *reinterpret_cast<const f32x4*>(xrowB + 2 * F_N);
            xprB1 = *reinterpret_cast<const f32x4*>(xrowB + 3 * F_N);
            f16x4 c0, c1, c2, c3;
            #pragma unroll
            for (int j = 0; j < 4; ++j) {
                c0[j] = (_Float16)a0[j]; c1[j] = (_Float16)a1[j];
                c2[j] = (_Float16)b0[j]; c3[j] = (_Float16)b1v[j];
            }
            *reinterpret_cast<f16x4*>(&xb[0][0][xr][xf0]) = c0;
            *reinterpret_cast<f16x4*>(&xb[0][1][xr][xf0]) = c1;
            *reinterpret_cast<f16x4*>(&xb[1][0][xr][xf0]) = c2;
            *reinterpret_cast<f16x4*>(&xb[1][1][xr][xf0]) = c3;
        }
        const float* xldA = xrowA + 4 * F_N;
        const float* xldB = xrowB + 4 * F_N;
        BAR();   // prologue sync #1

        // ax_G(0) -> axb[G][0] (direct write)
        #pragma unroll
        for (int G = 0; G < 2; ++G) {
            f16x8 xa0 = *reinterpret_cast<const f16x8*>(&xb[G][0][rowA][kg * 8]);
            f16x8 xa1 = *reinterpret_cast<const f16x8*>(&xb[G][0][rowA][32 + kg * 8]);
            f32x4 a0 = {bg[0], bg[0], bg[0], bg[0]};
            f32x4 a1 = {bg[1], bg[1], bg[1], bg[1]};
            f32x4 a2 = {bg[2], bg[2], bg[2], bg[2]};
            f32x4 a3 = {bg[3], bg[3], bg[3], bg[3]};
            a0 = MFMA(xa0, wxf[0][0], a0, 0, 0, 0);
            a1 = MFMA(xa0, wxf[1][0], a1, 0, 0, 0);
            a2 = MFMA(xa0, wxf[2][0], a2, 0, 0, 0);
            a3 = MFMA(xa0, wxf[3][0], a3, 0, 0, 0);
            a0 = MFMA(xa1, wxf[0][1], a0, 0, 0, 0);
            a1 = MFMA(xa1, wxf[1][1], a1, 0, 0, 0);
            a2 = MFMA(xa1, wxf[2][1], a2, 0, 0, 0);
            a3 = MFMA(xa1, wxf[3][1], a3, 0, 0, 0);
            *reinterpret_cast<f32x4*>(&axb[G][0][ut][0][lane][0]) = a0;
            *reinterpret_cast<f32x4*>(&axb[G][0][ut][1][lane][0]) = a1;
            *reinterpret_cast<f32x4*>(&axb[G][0][ut][2][lane][0]) = a2;
            *reinterpret_cast<f32x4*>(&axb[G][0][ut][3][lane][0]) = a3;
        }
        BAR();   // prologue sync #2

        f32x4 pax0, pax1, pax2, pax3;   // pending ax (flushed next window)

        // x window (group G, step t): read x_G(t+1) from xb[G][RB];
        // flush pending ax -> axb[FG][FB]; compute ax_G(t+1) -> pending;
        // stage x_G(t+2) -> xb[G][WB]; load x_G(t+4).
#define XWIN(G, RB, FLUSH, FG, FB, DO_XW, WB, XPR, DO_LOAD, XLD)               \
    {                                                                          \
        f16x8 xa0 = *reinterpret_cast<const f16x8*>(&xb[G][RB][rowA][kg * 8]); \
        f16x8 xa1 = *reinterpret_cast<const f16x8*>(&xb[G][RB][rowA][32 + kg * 8]); \
        if (FLUSH) {                                                           \
            *reinterpret_cast<f32x4*>(&axb[FG][FB][ut][0][lane][0]) = pax0;    \
            *reinterpret_cast<f32x4*>(&axb[FG][FB][ut][1][lane][0]) = pax1;    \
            *reinterpret_cast<f32x4*>(&axb[FG][FB][ut][2][lane][0]) = pax2;    \
            *reinterpret_cast<f32x4*>(&axb[FG][FB][ut][3][lane][0]) = pax3;    \
        }                                                                      \
        pax0 = (f32x4){bg[0], bg[0], bg[0], bg[0]};                            \
        pax1 = (f32x4){bg[1], bg[1], bg[1], bg[1]};                            \
        pax2 = (f32x4){bg[2], bg[2], bg[2], bg[2]};                            \
        pax3 = (f32x4){bg[3], bg[3], bg[3], bg[3]};                            \
        pax0 = MFMA(xa0, wxf[0][0], pax0, 0, 0, 0);                            \
        pax1 = MFMA(xa0, wxf[1][0], pax1, 0, 0, 0);                            \
        pax2 = MFMA(xa0, wxf[2][0], pax2, 0, 0, 0);                            \
        pax3 = MFMA(xa0, wxf[3][0], pax3, 0, 0, 0);                            \
        pax0 = MFMA(xa1, wxf[0][1], pax0, 0, 0, 0);                            \
        pax1 = MFMA(xa1, wxf[1][1], pax1, 0, 0, 0);                            \
        pax2 = MFMA(xa1, wxf[2][1], pax2, 0, 0, 0);                            \
        pax3 = MFMA(xa1, wxf[3][1], pax3, 0, 0, 0);                            \
        if (DO_XW) {                                                           \
            f16x4 xc;                                                          \
            xc[0] = (_Float16)XPR[0]; xc[1] = (_Float16)XPR[1];                \
            xc[2] = (_Float16)XPR[2]; xc[3] = (_Float16)XPR[3];                \
            *reinterpret_cast<f16x4*>(&xb[G][WB][xr][xf0]) = xc;               \
        }                                                                      \
        if (DO_LOAD) { XPR = *reinterpret_cast<const f32x4*>(XLD); XLD += F_N; } \
        BAR();                                                                 \
    }

        // peel it=0 (windows 0-3): first window has no pending flush
        XWIN(0, 1, 0, 0, 0, 1, 0, xprA0, 1, xldA)
        XWIN(1, 1, 1, 0, 1, 1, 0, xprB0, 1, xldB)
        XWIN(0, 0, 1, 1, 1, 1, 1, xprA1, 1, xldA)
        XWIN(1, 0, 1, 0, 0, 1, 1, xprB1, 1, xldB)
        for (int it = 1; it < 82; ++it) {   // windows 4..327
            XWIN(0, 1, 1, 1, 0, 1, 0, xprA0, 1, xldA)
            XWIN(1, 1, 1, 0, 1, 1, 0, xprB0, 1, xldB)
            XWIN(0, 0, 1, 1, 1, 1, 1, xprA1, 1, xldA)
            XWIN(1, 0, 1, 0, 0, 1, 1, xprB1, 1, xldB)
        }
        // tail: t=164..167 per group (windows 328..335)
        XWIN(0, 1, 1, 1, 0, 1, 0, xprA0, 0, xldA)   // ax_A(165), stage x_A(166)
        XWIN(1, 1, 1, 0, 1, 1, 0, xprB0, 0, xldB)   // ax_B(165), stage x_B(166)
        XWIN(0, 0, 1, 1, 1, 1, 1, xprA1, 0, xldA)   // ax_A(166), stage x_A(167)
        XWIN(1, 0, 1, 0, 0, 1, 1, xprB1, 0, xldB)   // ax_B(166), stage x_B(167)
        XWIN(0, 1, 1, 1, 0, 0, 0, xprA0, 0, xldA)   // ax_A(167)
        XWIN(1, 1, 1, 0, 1, 0, 0, xprB0, 0, xldB)   // ax_B(167)
        {   // window 334: flush ax_B(167) -> axb[1][1]
            *reinterpret_cast<f32x4*>(&axb[1][1][ut][0][lane][0]) = pax0;
            *reinterpret_cast<f32x4*>(&axb[1][1][ut][1][lane][0]) = pax1;
            *reinterpret_cast<f32x4*>(&axb[1][1][ut][2][lane][0]) = pax2;
            *reinterpret_cast<f32x4*>(&axb[1][1][ut][3][lane][0]) = pax3;
            BAR();
        }
        BAR();   // window 335
#undef XWIN
    } else {
        // ---------------- h-role ------------------------------------------
        f16x8 whf[4][2];
        #pragma unroll
        for (int g = 0; g < 4; ++g) {
            const float sc = (g == 2) ? LOG2E2 : LOG2E;
            #pragma unroll
            for (int ks = 0; ks < 2; ++ks) {
                f16x8 v;
                #pragma unroll
                for (int i = 0; i < 8; ++i) {
                    int k = ks * 32 + kg * 8 + i;
                    v[i] = (_Float16)((jv && k < H_N) ? Wh[k * 200 + g * H_N + jl] * sc : 0.0f);
                }
                whf[g][ks] = v;
            }
        }
        float cA0 = 0.f, cA1 = 0.f, cA2 = 0.f, cA3 = 0.f;
        float cB0 = 0.f, cB1 = 0.f, cB2 = 0.f, cB3 = 0.f;
        f16x4 ph;   // pending h (flushed next window)

        BAR();   // prologue sync #1
        BAR();   // prologue sync #2

#define GATE1(ii, cvar)                                                        \
    {                                                                          \
        float A_ = exp2_f(-zi[ii]);                                            \
        float B_ = exp2_f(-zg[ii]);                                            \
        float E_ = exp2_f(-zf[ii]);                                            \
        float sf_ = rcp_f(1.0f + E_);                                          \
        float r1_ = rcp_f((1.0f + A_) * (1.0f + B_));                          \
        float cn_ = fmaf(sf_, cvar, (1.0f - B_) * r1_);                        \
        cvar = cn_;                                                            \
        float C_ = exp2_f(-zo[ii]);                                            \
        float eD_ = fminf(-LOG2E2 * cn_, 80.0f);                               \
        float D_ = exp2_f(eD_);                                                \
        float r2_ = rcp_f((1.0f + C_) * (1.0f + D_));                          \
        ph[ii] = (_Float16)((1.0f - D_) * r2_);                                \
    }

        // h window (group G, step t): flush pending h -> hb[FG][FB];
        // read hb/axb[G][RB]; 8 MFMA; gates -> pending.
#define HWIN(G, RB, FLUSH, FG, FB, C0, C1, C2, C3)                             \
    {                                                                          \
        __builtin_amdgcn_s_setprio(1);                                         \
        f16x8 ha0 = *reinterpret_cast<const f16x8*>(&hb[G][RB][rowA][kg * 8]); \
        f16x8 ha1 = *reinterpret_cast<const f16x8*>(&hb[G][RB][rowA][32 + kg * 8]); \
        f32x4 zi = *reinterpret_cast<const f32x4*>(&axb[G][RB][ut][0][lane][0]); \
        f32x4 zf = *reinterpret_cast<const f32x4*>(&axb[G][RB][ut][1][lane][0]); \
        f32x4 zg = *reinterpret_cast<const f32x4*>(&axb[G][RB][ut][2][lane][0]); \
        f32x4 zo = *reinterpret_cast<const f32x4*>(&axb[G][RB][ut][3][lane][0]); \
        if (FLUSH) {                                                           \
            hb[FG][FB][kg * 4 + 0][jl] = ph[0];                                \
            hb[FG][FB][kg * 4 + 1][jl] = ph[1];                                \
            hb[FG][FB][kg * 4 + 2][jl] = ph[2];                                \
            hb[FG][FB][kg * 4 + 3][jl] = ph[3];                                \
        }                                                                      \
        zi = MFMA(ha0, whf[0][0], zi, 0, 0, 0);                                \
        zf = MFMA(ha0, whf[1][0], zf, 0, 0, 0);                                \
        zg = MFMA(ha0, whf[2][0], zg, 0, 0, 0);                                \
        zo = MFMA(ha0, whf[3][0], zo, 0, 0, 0);                                \
        zi = MFMA(ha1, whf[0][1], zi, 0, 0, 0);                                \
        zf = MFMA(ha1, whf[1][1], zf, 0, 0, 0);                                \
        zg = MFMA(ha1, whf[2][1], zg, 0, 0, 0);                                \
        zo = MFMA(ha1, whf[3][1], zo, 0, 0, 0);                                \
        GATE1(0, C0)                                                           \
        GATE1(1, C1)                                                           \
        GATE1(2, C2)                                                           \
        GATE1(3, C3)                                                           \
        __builtin_amdgcn_s_setprio(0);                                         \
        BAR();                                                                 \
    }

        // peel it=0 (windows 0-3)
        HWIN(0, 0, 0, 0, 0, cA0, cA1, cA2, cA3)
        HWIN(1, 0, 1, 0, 1, cB0, cB1, cB2, cB3)
        HWIN(0, 1, 1, 1, 1, cA0, cA1, cA2, cA3)
        HWIN(1, 1, 1, 0, 0, cB0, cB1, cB2, cB3)
        for (int it = 1; it < 84; ++it) {   // windows 4..335 (t=2..167 per group)
            HWIN(0, 0, 1, 1, 0, cA0, cA1, cA2, cA3)
            HWIN(1, 0, 1, 0, 1, cB0, cB1, cB2, cB3)
            HWIN(0, 1, 1, 1, 1, cA0, cA1, cA2, cA3)
            HWIN(1, 1, 1, 0, 0, cB0, cB1, cB2, cB3)
        }
        // final pending: h_B(168) -> hb[1][0]
        hb[1][0][kg * 4 + 0][jl] = ph[0];
        hb[1][0][kg * 4 + 1][jl] = ph[1];
        hb[1][0][kg * 4 + 2][jl] = ph[2];
        hb[1][0][kg * 4 + 3][jl] = ph[3];
#undef HWIN
#undef GATE1
    }
    __syncthreads();

    // ---- MLP head: relu(h@W1 + b1)@W2 + b2 + x[:, -1, 0] ------------------
    float (*hrelu)[HEAD_N] = reinterpret_cast<float (*)[HEAD_N]>(&axb[0][0][0][0][0][0]);
    {
        const int r1 = tid & 31;       // block row 0..31
        const int u1 = tid >> 5;       // 0..15
        float hrow[H_N];
        #pragma unroll
        for (int k = 0; k < H_N; ++k) hrow[k] = (float)hb[r1 >> 4][0][r1 & 15][k];
        for (int uu = u1; uu < HEAD_N; uu += 16) {
            float s = b1[uu];
            #pragma unroll
            for (int k = 0; k < H_N; ++k) s += hrow[k] * W1[k * HEAD_N + uu];
            hrelu[r1][uu] = fmaxf(s, 0.0f);
        }
    }
    __syncthreads();
    {
        const int r2 = tid >> 4;       // 0..31
        const int p  = tid & 15;
        float s = 0.0f;
        for (int uu = p; uu < HEAD_N; uu += 16) s += hrelu[r2][uu] * W2[uu];
        #pragma unroll
        for (int off = 8; off > 0; off >>= 1) s += __shfl_xor(s, off, 16);
        if (p == 0) {
            float res = x[(size_t)(R0 + r2) * ROWSTRIDE + (T_N - 1) * F_N + 0];
            out[R0 + r2] = s + b2[0] + res;
        }
    }
}

extern "C" void kernel_launch(void* const* d_in, const int* in_sizes, int n_in,
                              void* d_out, int out_size, void* d_ws, size_t ws_size,
                              hipStream_t stream) {
    const float* x  = (const float*)d_in[0];
    const float* Wx = (const float*)d_in[1];
    const float* Wh = (const float*)d_in[2];
    const float* b  = (const float*)d_in[3];
    const float* W1 = (const float*)d_in[4];
    const float* b1 = (const float*)d_in[5];
    const float* W2 = (const float*)d_in[6];
    const float* b2 = (const float*)d_in[7];
    float* out = (float*)d_out;

    lstm_fused<<<dim3(B_N / 32), dim3(512), 0, stream>>>(x, Wx, Wh, b, W1, b1, W2, b2, out);
}

// Round 9
// 151.559 us; speedup vs baseline: 1.0874x; 1.0874x over previous
//
#include <hip/hip_runtime.h>

// LSTM (B=8192, T=168, F=64, H=50) + MLP head, fused, f16 MFMA + fp32 state.
// Round 9: EXACT round-7 structure (producer/consumer wave split, merged-rcp
// gates, 1 lgkm-barrier/step) + one-time startup dephasing of co-resident
// blocks (4 phase classes ~1024 cy apart) to break barrier convoy lock
// between the 2 blocks sharing each CU.

#define B_N 8192
#define T_N 168
#define F_N 64
#define H_N 50
#define HEAD_N 100
#define ROWSTRIDE (T_N * F_N)  // 10752

typedef _Float16 f16x8 __attribute__((ext_vector_type(8)));
typedef _Float16 f16x4 __attribute__((ext_vector_type(4)));
typedef float    f32x4 __attribute__((ext_vector_type(4)));

#define LOG2E  1.4426950408889634f
#define LOG2E2 2.8853900817779268f

#define MFMA __builtin_amdgcn_mfma_f32_16x16x32_f16

// LDS-only barrier: drain own LDS ops, barrier, compiler fence both sides.
#define BAR()                                                        \
    do {                                                             \
        asm volatile("s_waitcnt lgkmcnt(0)" ::: "memory");           \
        __builtin_amdgcn_s_barrier();                                \
        asm volatile("" ::: "memory");                               \
    } while (0)

__device__ __forceinline__ float rcp_f(float v) { return __builtin_amdgcn_rcpf(v); }
#if __has_builtin(__builtin_amdgcn_exp2f)
__device__ __forceinline__ float exp2_f(float v) { return __builtin_amdgcn_exp2f(v); }
#else
__device__ __forceinline__ float exp2_f(float v) { return __expf(0.6931471805599453f * v); }
#endif

__launch_bounds__(512, 4)
__global__ void lstm_fused(const float* __restrict__ x,
                           const float* __restrict__ Wx,
                           const float* __restrict__ Wh,
                           const float* __restrict__ b,
                           const float* __restrict__ W1,
                           const float* __restrict__ b1,
                           const float* __restrict__ W2,
                           const float* __restrict__ b2,
                           float* __restrict__ out)
{
    __shared__ alignas(16) _Float16 xb[2][16][72];        // xb[t&1] = x(t)
    __shared__ alignas(16) _Float16 hb[2][16][72];        // hb[t&1] = h(t)
    __shared__ alignas(16) float axb[2][4][4][64][4];     // [P][tile][gate][lane][4]
    __shared__ float hrelu[16][HEAD_N];

    const int tid  = threadIdx.x;
    const int lane = tid & 63;
    const int w    = tid >> 6;         // 0..7; 0-3 x-waves, 4-7 h-waves
    const int ut   = w & 3;            // unit-tile (16 units each)
    const int rowA = lane & 15;        // A-frag row == C-frag col
    const int kg   = lane >> 4;        // k-group 0..3
    const int R0   = blockIdx.x * 16;  // batch rows of this block
    const int jl   = ut * 16 + rowA;   // unit index 0..63
    const bool jv  = (jl < H_N);

    // ---- role-specific weight fragments (VGPR-resident, exp2-prescaled) --
    f16x8 wxf[4][2], whf[4][2];
    float bg[4];
    if (w < 4) {
        #pragma unroll
        for (int g = 0; g < 4; ++g) {
            const float sc = (g == 2) ? LOG2E2 : LOG2E;
            bg[g] = jv ? b[g * H_N + jl] * sc : 0.0f;
            #pragma unroll
            for (int ks = 0; ks < 2; ++ks) {
                f16x8 v;
                #pragma unroll
                for (int i = 0; i < 8; ++i) {
                    int k = ks * 32 + kg * 8 + i;     // same k-map as A-frags
                    v[i] = (_Float16)(jv ? Wx[k * 200 + g * H_N + jl] * sc : 0.0f);
                }
                wxf[g][ks] = v;
            }
        }
    } else {
        #pragma unroll
        for (int g = 0; g < 4; ++g) {
            const float sc = (g == 2) ? LOG2E2 : LOG2E;
            #pragma unroll
            for (int ks = 0; ks < 2; ++ks) {
                f16x8 v;
                #pragma unroll
                for (int i = 0; i < 8; ++i) {
                    int k = ks * 32 + kg * 8 + i;
                    v[i] = (_Float16)((jv && k < H_N) ? Wh[k * 200 + g * H_N + jl] * sc : 0.0f);
                }
                whf[g][ks] = v;
            }
        }
    }

    float c0 = 0.f, c1 = 0.f, c2 = 0.f, c3 = 0.f;   // h-wave fp32 cell state

    // zero h(0)
    for (int idx = tid; idx < 16 * 72; idx += 512)
        ((_Float16*)hb[0])[idx] = (_Float16)0.0f;

    // x staging map (x-waves = tid 0..255): (row tid>>4, 4 floats), coalesced
    const int xr  = (tid >> 4) & 15;
    const int xf0 = (tid & 15) * 4;
    const float* xrow = x + (size_t)(R0 + xr) * ROWSTRIDE + xf0;
    f32x4 xpr0, xpr1;     // in-flight x rows: xpr[t&1] LDS-written at step t
    if (w < 4) {
        f32x4 v0 = *reinterpret_cast<const f32x4*>(xrow);
        f32x4 v1 = *reinterpret_cast<const f32x4*>(xrow + F_N);
        xpr0 = *reinterpret_cast<const f32x4*>(xrow + 2 * F_N);   // x(2)
        xpr1 = *reinterpret_cast<const f32x4*>(xrow + 3 * F_N);   // x(3)
        f16x4 a, c4;
        #pragma unroll
        for (int j = 0; j < 4; ++j) { a[j] = (_Float16)v0[j]; c4[j] = (_Float16)v1[j]; }
        *reinterpret_cast<f16x4*>(&xb[0][xr][xf0]) = a;   // x(0)
        *reinterpret_cast<f16x4*>(&xb[1][xr][xf0]) = c4;  // x(1)
    }
    const float* xld = xrow + 4 * F_N;   // next global load: x(4)
    __syncthreads();

    if (w < 4) {   // prologue: ax(0) = b + x(0)@Wx -> axb[0]
        f16x8 xa0 = *reinterpret_cast<const f16x8*>(&xb[0][rowA][kg * 8]);
        f16x8 xa1 = *reinterpret_cast<const f16x8*>(&xb[0][rowA][32 + kg * 8]);
        f32x4 a0 = {bg[0], bg[0], bg[0], bg[0]};
        f32x4 a1 = {bg[1], bg[1], bg[1], bg[1]};
        f32x4 a2 = {bg[2], bg[2], bg[2], bg[2]};
        f32x4 a3 = {bg[3], bg[3], bg[3], bg[3]};
        a0 = MFMA(xa0, wxf[0][0], a0, 0, 0, 0);
        a1 = MFMA(xa0, wxf[1][0], a1, 0, 0, 0);
        a2 = MFMA(xa0, wxf[2][0], a2, 0, 0, 0);
        a3 = MFMA(xa0, wxf[3][0], a3, 0, 0, 0);
        a0 = MFMA(xa1, wxf[0][1], a0, 0, 0, 0);
        a1 = MFMA(xa1, wxf[1][1], a1, 0, 0, 0);
        a2 = MFMA(xa1, wxf[2][1], a2, 0, 0, 0);
        a3 = MFMA(xa1, wxf[3][1], a3, 0, 0, 0);
        *reinterpret_cast<f32x4*>(&axb[0][ut][0][lane][0]) = a0;
        *reinterpret_cast<f32x4*>(&axb[0][ut][1][lane][0]) = a1;
        *reinterpret_cast<f32x4*>(&axb[0][ut][2][lane][0]) = a2;
        *reinterpret_cast<f32x4*>(&axb[0][ut][3][lane][0]) = a3;
    }
    __syncthreads();

    // ---- one-time dephase: break barrier convoy lock between co-resident
    // blocks. 4 phase classes ~1024 cy apart; class covers both plausible
    // same-CU pairings (consecutive blockIdx, or b and b+256 under 8-XCD
    // round-robin). Results unaffected.
    {
        const int phase = (blockIdx.x & 1) | (((blockIdx.x >> 8) & 1) << 1);
        for (int i = 0; i < phase; ++i) __builtin_amdgcn_s_sleep(15);
    }

    // gates v2: merged-rcp pairs, exp2 domain (weights prescaled; g by 2x).
#define GATE1(PW, ii, cvar)                                                    \
    {                                                                          \
        float A_ = exp2_f(-zi[ii]);                                            \
        float B_ = exp2_f(-zg[ii]);                                            \
        float F_ = exp2_f(-zf[ii]);                                            \
        float sf_ = rcp_f(1.0f + F_);                                          \
        float r1_ = rcp_f((1.0f + A_) * (1.0f + B_));                          \
        float cn_ = fmaf(sf_, cvar, (1.0f - B_) * r1_);                        \
        cvar = cn_;                                                            \
        float C_ = exp2_f(-zo[ii]);                                            \
        float eD_ = fminf(-LOG2E2 * cn_, 80.0f);                               \
        float D_ = exp2_f(eD_);                                                \
        float r2_ = rcp_f((1.0f + C_) * (1.0f + D_));                          \
        hb[PW][kg * 4 + ii][jl] = (_Float16)((1.0f - D_) * r2_);               \
    }

#define XSTEP(P, DO_XW, DO_LOAD)                                               \
    {                                                                          \
        f16x8 xa0 = *reinterpret_cast<const f16x8*>(&xb[P ^ 1][rowA][kg * 8]);      \
        f16x8 xa1 = *reinterpret_cast<const f16x8*>(&xb[P ^ 1][rowA][32 + kg * 8]); \
        f32x4 a0 = {bg[0], bg[0], bg[0], bg[0]};                               \
        f32x4 a1 = {bg[1], bg[1], bg[1], bg[1]};                               \
        f32x4 a2 = {bg[2], bg[2], bg[2], bg[2]};                               \
        f32x4 a3 = {bg[3], bg[3], bg[3], bg[3]};                               \
        a0 = MFMA(xa0, wxf[0][0], a0, 0, 0, 0);                                \
        a1 = MFMA(xa0, wxf[1][0], a1, 0, 0, 0);                                \
        a2 = MFMA(xa0, wxf[2][0], a2, 0, 0, 0);                                \
        a3 = MFMA(xa0, wxf[3][0], a3, 0, 0, 0);                                \
        a0 = MFMA(xa1, wxf[0][1], a0, 0, 0, 0);                                \
        a1 = MFMA(xa1, wxf[1][1], a1, 0, 0, 0);                                \
        a2 = MFMA(xa1, wxf[2][1], a2, 0, 0, 0);                                \
        a3 = MFMA(xa1, wxf[3][1], a3, 0, 0, 0);                                \
        *reinterpret_cast<f32x4*>(&axb[P ^ 1][ut][0][lane][0]) = a0;           \
        *reinterpret_cast<f32x4*>(&axb[P ^ 1][ut][1][lane][0]) = a1;           \
        *reinterpret_cast<f32x4*>(&axb[P ^ 1][ut][2][lane][0]) = a2;           \
        *reinterpret_cast<f32x4*>(&axb[P ^ 1][ut][3][lane][0]) = a3;           \
        if (DO_XW) {                                                           \
            f16x4 xc;                                                          \
            xc[0] = (_Float16)xpr##P[0]; xc[1] = (_Float16)xpr##P[1];          \
            xc[2] = (_Float16)xpr##P[2]; xc[3] = (_Float16)xpr##P[3];          \
            *reinterpret_cast<f16x4*>(&xb[P][xr][xf0]) = xc;                   \
        }                                                                      \
        if (DO_LOAD) { xpr##P = *reinterpret_cast<const f32x4*>(xld); xld += F_N; } \
        BAR();                                                                 \
    }

#define HSTEP(P)                                                               \
    {                                                                          \
        __builtin_amdgcn_s_setprio(1);                                         \
        f16x8 ha0 = *reinterpret_cast<const f16x8*>(&hb[P][rowA][kg * 8]);     \
        f16x8 ha1 = *reinterpret_cast<const f16x8*>(&hb[P][rowA][32 + kg * 8]);\
        f32x4 zi = *reinterpret_cast<const f32x4*>(&axb[P][ut][0][lane][0]);   \
        f32x4 zf = *reinterpret_cast<const f32x4*>(&axb[P][ut][1][lane][0]);   \
        f32x4 zg = *reinterpret_cast<const f32x4*>(&axb[P][ut][2][lane][0]);   \
        f32x4 zo = *reinterpret_cast<const f32x4*>(&axb[P][ut][3][lane][0]);   \
        zi = MFMA(ha0, whf[0][0], zi, 0, 0, 0);                                \
        zf = MFMA(ha0, whf[1][0], zf, 0, 0, 0);                                \
        zg = MFMA(ha0, whf[2][0], zg, 0, 0, 0);                                \
        zo = MFMA(ha0, whf[3][0], zo, 0, 0, 0);                                \
        zi = MFMA(ha1, whf[0][1], zi, 0, 0, 0);                                \
        zf = MFMA(ha1, whf[1][1], zf, 0, 0, 0);                                \
        zg = MFMA(ha1, whf[2][1], zg, 0, 0, 0);                                \
        zo = MFMA(ha1, whf[3][1], zo, 0, 0, 0);                                \
        GATE1(P ^ 1, 0, c0)                                                    \
        GATE1(P ^ 1, 1, c1)                                                    \
        GATE1(P ^ 1, 2, c2)                                                    \
        GATE1(P ^ 1, 3, c3)                                                    \
        __builtin_amdgcn_s_setprio(0);                                         \
        BAR();                                                                 \
    }

    // Both role-loops execute EXACTLY 168 barriers (mirror structure).
    if (w < 4) {
        for (int it = 0; it < 82; ++it) {   // t = 0..163
            XSTEP(0, 1, 1)
            XSTEP(1, 1, 1)
        }
        XSTEP(0, 1, 0)   // t=164: ax(165), write x(166)
        XSTEP(1, 1, 0)   // t=165: ax(166), write x(167)
        XSTEP(0, 0, 0)   // t=166: ax(167)
        BAR();           // t=167: x-waves just sync
    } else {
        for (int it = 0; it < 82; ++it) {   // t = 0..163
            HSTEP(0)
            HSTEP(1)
        }
        HSTEP(0)   // t=164
        HSTEP(1)   // t=165
        HSTEP(0)   // t=166
        HSTEP(1)   // t=167: final h(168) -> hb[0]
    }
#undef XSTEP
#undef HSTEP
#undef GATE1

    // ---- MLP head: relu(h@W1 + b1)@W2 + b2 + x[:, -1, 0] ------------------
    if (tid < 256) {
        const int r1 = tid & 15;
        const int u1 = tid >> 4;
        float hrow[H_N];
        #pragma unroll
        for (int k = 0; k < H_N; ++k) hrow[k] = (float)hb[0][r1][k];
        for (int uu = u1; uu < HEAD_N; uu += 16) {
            float s = b1[uu];
            #pragma unroll
            for (int k = 0; k < H_N; ++k) s += hrow[k] * W1[k * HEAD_N + uu];
            hrelu[r1][uu] = fmaxf(s, 0.0f);
        }
    }
    __syncthreads();
    if (tid < 256) {
        const int r2 = tid >> 4;
        const int p  = tid & 15;
        float s = 0.0f;
        for (int uu = p; uu < HEAD_N; uu += 16) s += hrelu[r2][uu] * W2[uu];
        #pragma unroll
        for (int off = 8; off > 0; off >>= 1) s += __shfl_xor(s, off, 16);
        if (p == 0) {
            float res = x[(size_t)(R0 + r2) * ROWSTRIDE + (T_N - 1) * F_N + 0];
            out[R0 + r2] = s + b2[0] + res;
        }
    }
}

extern "C" void kernel_launch(void* const* d_in, const int* in_sizes, int n_in,
                              void* d_out, int out_size, void* d_ws, size_t ws_size,
                              hipStream_t stream) {
    const float* x  = (const float*)d_in[0];
    const float* Wx = (const float*)d_in[1];
    const float* Wh = (const float*)d_in[2];
    const float* b  = (const float*)d_in[3];
    const float* W1 = (const float*)d_in[4];
    const float* b1 = (const float*)d_in[5];
    const float* W2 = (const float*)d_in[6];
    const float* b2 = (const float*)d_in[7];
    float* out = (float*)d_out;

    lstm_fused<<<dim3(B_N / 16), dim3(512), 0, stream>>>(x, Wx, Wh, b, W1, b1, W2, b2, out);
}